// Round 1
// baseline (534.719 us; speedup 1.0000x reference)
//
#include <hip/hip_runtime.h>
#include <math.h>

namespace {

constexpr int SEQ  = 300;
constexpr int DM   = 64;
constexpr int DFFN = 256;
constexpr int NBAT = 256;
constexpr int ROWS = NBAT * SEQ;   // 76800
constexpr float EPS = 1e-5f;

struct BranchArgs {
  const float *W, *b, *Wc, *bc, *gE, *betaE, *gH, *betaH;
  float* out;
};
struct QkvArgs {
  const float *state, *H;
  BranchArgs br[3];
};

__device__ __forceinline__ float4 ld4(const float* p) { return *reinterpret_cast<const float4*>(p); }

// ---------------------------------------------------------------------------
// K1: q/k/v = LN(state@W + b) * LN(H@Wc + bc)   -> 3x [ROWS][64] in workspace
// 64 rows per block, 4x4 register tiles, H staged in 4 K-chunks of 64.
// ---------------------------------------------------------------------------
__global__ __launch_bounds__(256) void tb_qkv(QkvArgs A)
{
  __shared__ float s_t[64][68];   // state^T [i][r]
  __shared__ float h_t[64][68];   // H^T chunk [i][r]
  const int t  = threadIdx.x;
  const int jg = t & 15, rg = t >> 4;
  const int j0 = jg * 4, r0 = rg * 4;
  const int rowbase = blockIdx.x * 64;

  #pragma unroll
  for (int it = 0; it < 4; ++it) {
    const int p = it * 256 + t;
    const int row = p >> 4, c4 = (p & 15) * 4;
    const float4 f = ld4(&A.state[(rowbase + row) * DM + c4]);
    s_t[c4 + 0][row] = f.x; s_t[c4 + 1][row] = f.y;
    s_t[c4 + 2][row] = f.z; s_t[c4 + 3][row] = f.w;
  }
  __syncthreads();

  float e[3][4][4];
  float h[3][4][4];
  #pragma unroll
  for (int br = 0; br < 3; ++br) {
    float bb[4]; *(float4*)bb = ld4(&A.br[br].b[j0]);
    float bb2[4]; *(float4*)bb2 = ld4(&A.br[br].bc[j0]);
    #pragma unroll
    for (int rr = 0; rr < 4; ++rr)
      #pragma unroll
      for (int jj = 0; jj < 4; ++jj) { e[br][rr][jj] = bb[jj]; h[br][rr][jj] = bb2[jj]; }
  }

  // E-part: state @ W (K = 64)
  #pragma unroll 1
  for (int i = 0; i < 64; i += 4) {
    float sv[4][4];
    #pragma unroll
    for (int u = 0; u < 4; ++u) *(float4*)sv[u] = *(const float4*)&s_t[i + u][r0];
    #pragma unroll
    for (int u = 0; u < 4; ++u) {
      #pragma unroll
      for (int br = 0; br < 3; ++br) {
        float wv[4]; *(float4*)wv = ld4(&A.br[br].W[(i + u) * DM + j0]);
        #pragma unroll
        for (int rr = 0; rr < 4; ++rr)
          #pragma unroll
          for (int jj = 0; jj < 4; ++jj)
            e[br][rr][jj] = fmaf(sv[u][rr], wv[jj], e[br][rr][jj]);
      }
    }
  }

  // H-part: H @ Wc (K = 256, 4 staged chunks)
  #pragma unroll 1
  for (int c = 0; c < 4; ++c) {
    __syncthreads();
    #pragma unroll
    for (int it = 0; it < 4; ++it) {
      const int p = it * 256 + t;
      const int row = p >> 4, c4 = (p & 15) * 4;
      const float4 f = ld4(&A.H[(rowbase + row) * DFFN + c * 64 + c4]);
      h_t[c4 + 0][row] = f.x; h_t[c4 + 1][row] = f.y;
      h_t[c4 + 2][row] = f.z; h_t[c4 + 3][row] = f.w;
    }
    __syncthreads();
    #pragma unroll 1
    for (int i = 0; i < 64; i += 4) {
      float sv[4][4];
      #pragma unroll
      for (int u = 0; u < 4; ++u) *(float4*)sv[u] = *(const float4*)&h_t[i + u][r0];
      #pragma unroll
      for (int u = 0; u < 4; ++u) {
        #pragma unroll
        for (int br = 0; br < 3; ++br) {
          float wv[4]; *(float4*)wv = ld4(&A.br[br].Wc[(c * 64 + i + u) * DM + j0]);
          #pragma unroll
          for (int rr = 0; rr < 4; ++rr)
            #pragma unroll
            for (int jj = 0; jj < 4; ++jj)
              h[br][rr][jj] = fmaf(sv[u][rr], wv[jj], h[br][rr][jj]);
        }
      }
    }
  }

  // LN(e) * LN(h) -> store
  #pragma unroll
  for (int br = 0; br < 3; ++br) {
    float gE[4], bE[4], gH[4], bH[4];
    *(float4*)gE = ld4(&A.br[br].gE[j0]);
    *(float4*)bE = ld4(&A.br[br].betaE[j0]);
    *(float4*)gH = ld4(&A.br[br].gH[j0]);
    *(float4*)bH = ld4(&A.br[br].betaH[j0]);
    #pragma unroll
    for (int rr = 0; rr < 4; ++rr) {
      float s1 = 0.f, s2 = 0.f, t1 = 0.f, t2 = 0.f;
      #pragma unroll
      for (int jj = 0; jj < 4; ++jj) {
        s1 += e[br][rr][jj]; s2 += e[br][rr][jj] * e[br][rr][jj];
        t1 += h[br][rr][jj]; t2 += h[br][rr][jj] * h[br][rr][jj];
      }
      #pragma unroll
      for (int m = 1; m <= 8; m <<= 1) {
        s1 += __shfl_xor(s1, m, 64); s2 += __shfl_xor(s2, m, 64);
        t1 += __shfl_xor(t1, m, 64); t2 += __shfl_xor(t2, m, 64);
      }
      const float me = s1 * (1.f / 64.f);
      const float re = rsqrtf(s2 * (1.f / 64.f) - me * me + EPS);
      const float mh = t1 * (1.f / 64.f);
      const float rh = rsqrtf(t2 * (1.f / 64.f) - mh * mh + EPS);
      float ov[4];
      #pragma unroll
      for (int jj = 0; jj < 4; ++jj) {
        const float en = (e[br][rr][jj] - me) * re * gE[jj] + bE[jj];
        const float hn = (h[br][rr][jj] - mh) * rh * gH[jj] + bH[jj];
        ov[jj] = en * hn;
      }
      *(float4*)&A.br[br].out[(rowbase + r0 + rr) * DM + j0] = *(float4*)ov;
    }
  }
}

// ---------------------------------------------------------------------------
// K2: per (batch, head, 64-q-row tile): scores = QK^T/sqrt(32) -> softmax -> PV
// ---------------------------------------------------------------------------
__global__ __launch_bounds__(256) void tb_attn(const float* __restrict__ q, const float* __restrict__ k,
                                               const float* __restrict__ v, float* __restrict__ ao)
{
  __shared__ float Qt[32][68];        // Q^T [d][qr]
  __shared__ float Sm[64][308];       // scores / probs (stride 308: banks ok)
  __shared__ float KV[300 * 36];      // union: K^T [d][kk] stride 304, then V [kk][d] stride 36

  const int t = threadIdx.x;
  const int b = blockIdx.z, hh = blockIdx.y, qt = blockIdx.x;
  const int qbase = qt * 64;
  const int base = (b * SEQ) * DM + hh * 32;

  #pragma unroll
  for (int it = 0; it < 2; ++it) {
    const int p = it * 256 + t;
    const int row = p >> 3, c4 = (p & 7) * 4;
    float4 f = make_float4(0.f, 0.f, 0.f, 0.f);
    if (qbase + row < SEQ) f = ld4(&q[base + (qbase + row) * DM + c4]);
    Qt[c4 + 0][row] = f.x; Qt[c4 + 1][row] = f.y; Qt[c4 + 2][row] = f.z; Qt[c4 + 3][row] = f.w;
  }
  #pragma unroll
  for (int it = 0; it < 10; ++it) {
    const int p = it * 256 + t;
    if (p < 2400) {
      const int row = p >> 3, c4 = (p & 7) * 4;
      const float4 f = ld4(&k[base + row * DM + c4]);
      KV[(c4 + 0) * 304 + row] = f.x; KV[(c4 + 1) * 304 + row] = f.y;
      KV[(c4 + 2) * 304 + row] = f.z; KV[(c4 + 3) * 304 + row] = f.w;
    }
  }
  if (t < 128) KV[(t >> 2) * 304 + 300 + (t & 3)] = 0.f;   // zero K^T pad cols
  __syncthreads();

  const int jg = t & 15, rg = t >> 4;
  const int j0 = jg * 4, r0 = rg * 4;
  constexpr float scale = 0.17677669529663687f;  // 1/sqrt(32)

  // scores GEMM: 64 x 300, K = 32, in 5 col-chunks of 64
  #pragma unroll 1
  for (int c = 0; c < 5; ++c) {
    float acc[4][4];
    #pragma unroll
    for (int rr = 0; rr < 4; ++rr)
      #pragma unroll
      for (int jj = 0; jj < 4; ++jj) acc[rr][jj] = 0.f;
    #pragma unroll 2
    for (int i = 0; i < 32; i += 4) {
      float qv[4][4], kv[4][4];
      #pragma unroll
      for (int u = 0; u < 4; ++u) *(float4*)qv[u] = *(const float4*)&Qt[i + u][r0];
      #pragma unroll
      for (int u = 0; u < 4; ++u) *(float4*)kv[u] = *(const float4*)&KV[(i + u) * 304 + c * 64 + j0];
      #pragma unroll
      for (int u = 0; u < 4; ++u)
        #pragma unroll
        for (int rr = 0; rr < 4; ++rr)
          #pragma unroll
          for (int jj = 0; jj < 4; ++jj)
            acc[rr][jj] = fmaf(qv[u][rr], kv[u][jj], acc[rr][jj]);
    }
    const int kc = c * 64 + j0;
    if (kc <= 296) {
      #pragma unroll
      for (int rr = 0; rr < 4; ++rr) {
        float ov[4];
        #pragma unroll
        for (int jj = 0; jj < 4; ++jj) ov[jj] = acc[rr][jj] * scale;
        *(float4*)&Sm[r0 + rr][kc] = *(float4*)ov;
      }
    }
  }
  __syncthreads();

  // stage V over the K^T region (K no longer needed)
  #pragma unroll
  for (int it = 0; it < 10; ++it) {
    const int p = it * 256 + t;
    if (p < 2400) {
      const int row = p >> 3, c4 = (p & 7) * 4;
      const float4 f = ld4(&v[base + row * DM + c4]);
      *(float4*)&KV[row * 36 + c4] = f;
    }
  }

  // softmax: each wave owns 16 rows
  {
    const int wv = t >> 6, lane = t & 63;
    #pragma unroll 1
    for (int u = 0; u < 16; ++u) {
      const int r = wv * 16 + u;
      float x[5];
      #pragma unroll
      for (int s5 = 0; s5 < 4; ++s5) x[s5] = Sm[r][lane + 64 * s5];
      x[4] = (lane < 44) ? Sm[r][lane + 256] : -1e30f;
      float mx = fmaxf(fmaxf(fmaxf(x[0], x[1]), fmaxf(x[2], x[3])), x[4]);
      #pragma unroll
      for (int m = 1; m <= 32; m <<= 1) mx = fmaxf(mx, __shfl_xor(mx, m, 64));
      float sum = 0.f;
      #pragma unroll
      for (int s5 = 0; s5 < 5; ++s5) { x[s5] = __expf(x[s5] - mx); sum += x[s5]; }
      #pragma unroll
      for (int m = 1; m <= 32; m <<= 1) sum += __shfl_xor(sum, m, 64);
      const float inv = 1.f / sum;
      #pragma unroll
      for (int s5 = 0; s5 < 4; ++s5) Sm[r][lane + 64 * s5] = x[s5] * inv;
      if (lane < 44) Sm[r][lane + 256] = x[4] * inv;
    }
  }
  __syncthreads();

  // PV: thread = (2 q-rows: qp, qp+32) x (4 d-cols)
  {
    const int d0 = (t & 7) * 4, qp = t >> 3;
    float a0[4] = {0.f, 0.f, 0.f, 0.f}, a1[4] = {0.f, 0.f, 0.f, 0.f};
    #pragma unroll 2
    for (int kk = 0; kk < 300; kk += 4) {
      float p0[4], p1[4];
      *(float4*)p0 = *(const float4*)&Sm[qp][kk];
      *(float4*)p1 = *(const float4*)&Sm[qp + 32][kk];
      #pragma unroll
      for (int u = 0; u < 4; ++u) {
        float vv[4]; *(float4*)vv = *(const float4*)&KV[(kk + u) * 36 + d0];
        #pragma unroll
        for (int jj = 0; jj < 4; ++jj) {
          a0[jj] = fmaf(p0[u], vv[jj], a0[jj]);
          a1[jj] = fmaf(p1[u], vv[jj], a1[jj]);
        }
      }
    }
    if (qbase + qp < SEQ)      *(float4*)&ao[base + (qbase + qp) * DM + d0] = *(float4*)a0;
    if (qbase + qp + 32 < SEQ) *(float4*)&ao[base + (qbase + qp + 32) * DM + d0] = *(float4*)a1;
  }
}

// ---------------------------------------------------------------------------
// K3: Z1 = state + attn; Z2 = LN(Z1); Z3 = gelu(Z2@W1+b1); out = Z1 + Z3@W2 + b2
// ---------------------------------------------------------------------------
__global__ __launch_bounds__(256) void tb_ffn(const float* __restrict__ state, const float* __restrict__ ao,
    const float* __restrict__ W1, const float* __restrict__ b1,
    const float* __restrict__ W2, const float* __restrict__ b2,
    const float* __restrict__ g1, const float* __restrict__ beta1,
    float* __restrict__ out)
{
  __shared__ float Z1[64][68];
  __shared__ float Z2t[64][68];   // Z2^T [i][r]
  __shared__ float Z3t[64][68];   // gelu chunk ^T [i][r]
  const int t = threadIdx.x;
  const int rowbase = blockIdx.x * 64;

  #pragma unroll
  for (int it = 0; it < 4; ++it) {
    const int p = it * 256 + t;
    const int row = p >> 4, c4 = (p & 15) * 4;
    const float4 a = ld4(&state[(rowbase + row) * DM + c4]);
    const float4 bo = ld4(&ao[(rowbase + row) * DM + c4]);
    float zv[4] = {a.x + bo.x, a.y + bo.y, a.z + bo.z, a.w + bo.w};
    *(float4*)&Z1[row][c4] = *(float4*)zv;
  }
  __syncthreads();

  {
    const int wv = t >> 6, lane = t & 63;
    const float g = g1[lane], be = beta1[lane];
    #pragma unroll 1
    for (int u = 0; u < 16; ++u) {
      const int r = wv * 16 + u;
      const float x = Z1[r][lane];
      float s1 = x, s2 = x * x;
      #pragma unroll
      for (int m = 1; m <= 32; m <<= 1) { s1 += __shfl_xor(s1, m, 64); s2 += __shfl_xor(s2, m, 64); }
      const float mean = s1 * (1.f / 64.f);
      const float rstd = rsqrtf(s2 * (1.f / 64.f) - mean * mean + EPS);
      Z2t[lane][r] = (x - mean) * rstd * g + be;
    }
  }
  __syncthreads();

  const int jg = t & 15, rg = t >> 4;
  const int j0 = jg * 4, r0 = rg * 4;
  float acc4[4][4];
  {
    float bb[4]; *(float4*)bb = ld4(&b2[j0]);
    #pragma unroll
    for (int rr = 0; rr < 4; ++rr)
      #pragma unroll
      for (int jj = 0; jj < 4; ++jj) acc4[rr][jj] = bb[jj];
  }

  #pragma unroll 1
  for (int c = 0; c < 4; ++c) {
    float acc1[4][4];
    {
      float bb[4]; *(float4*)bb = ld4(&b1[c * 64 + j0]);
      #pragma unroll
      for (int rr = 0; rr < 4; ++rr)
        #pragma unroll
        for (int jj = 0; jj < 4; ++jj) acc1[rr][jj] = bb[jj];
    }
    #pragma unroll 2
    for (int i = 0; i < 64; i += 4) {
      float zv[4][4];
      #pragma unroll
      for (int u = 0; u < 4; ++u) *(float4*)zv[u] = *(const float4*)&Z2t[i + u][r0];
      #pragma unroll
      for (int u = 0; u < 4; ++u) {
        float wv[4]; *(float4*)wv = ld4(&W1[(i + u) * DFFN + c * 64 + j0]);
        #pragma unroll
        for (int rr = 0; rr < 4; ++rr)
          #pragma unroll
          for (int jj = 0; jj < 4; ++jj)
            acc1[rr][jj] = fmaf(zv[u][rr], wv[jj], acc1[rr][jj]);
      }
    }
    #pragma unroll
    for (int rr = 0; rr < 4; ++rr)
      #pragma unroll
      for (int jj = 0; jj < 4; ++jj) {
        const float xg = acc1[rr][jj];
        Z3t[j0 + jj][r0 + rr] = 0.5f * xg * (1.f + erff(xg * 0.70710678118654752f));
      }
    __syncthreads();
    #pragma unroll 2
    for (int i = 0; i < 64; i += 4) {
      float zv[4][4];
      #pragma unroll
      for (int u = 0; u < 4; ++u) *(float4*)zv[u] = *(const float4*)&Z3t[i + u][r0];
      #pragma unroll
      for (int u = 0; u < 4; ++u) {
        float wv[4]; *(float4*)wv = ld4(&W2[(c * 64 + i + u) * DM + j0]);
        #pragma unroll
        for (int rr = 0; rr < 4; ++rr)
          #pragma unroll
          for (int jj = 0; jj < 4; ++jj)
            acc4[rr][jj] = fmaf(zv[u][rr], wv[jj], acc4[rr][jj]);
      }
    }
    __syncthreads();
  }

  #pragma unroll
  for (int rr = 0; rr < 4; ++rr) {
    float ov[4];
    const float* z1p = &Z1[r0 + rr][j0];
    #pragma unroll
    for (int jj = 0; jj < 4; ++jj) ov[jj] = z1p[jj] + acc4[rr][jj];
    *(float4*)&out[(rowbase + r0 + rr) * DM + j0] = *(float4*)ov;
  }
}

} // namespace

extern "C" void kernel_launch(void* const* d_in, const int* in_sizes, int n_in,
                              void* d_out, int out_size, void* d_ws, size_t ws_size,
                              hipStream_t stream)
{
  const float* state = (const float*)d_in[0];
  const float* H     = (const float*)d_in[1];
  const float* Wq  = (const float*)d_in[2];  const float* bq  = (const float*)d_in[3];
  const float* Wk  = (const float*)d_in[4];  const float* bk  = (const float*)d_in[5];
  const float* Wv  = (const float*)d_in[6];  const float* bv  = (const float*)d_in[7];
  const float* Wcq = (const float*)d_in[8];  const float* bcq = (const float*)d_in[9];
  const float* Wck = (const float*)d_in[10]; const float* bck = (const float*)d_in[11];
  const float* Wcv = (const float*)d_in[12]; const float* bcv = (const float*)d_in[13];
  const float* gQE = (const float*)d_in[14]; const float* betaQE = (const float*)d_in[15];
  const float* gKE = (const float*)d_in[16]; const float* betaKE = (const float*)d_in[17];
  const float* gVE = (const float*)d_in[18]; const float* betaVE = (const float*)d_in[19];
  const float* gQH = (const float*)d_in[20]; const float* betaQH = (const float*)d_in[21];
  const float* gKH = (const float*)d_in[22]; const float* betaKH = (const float*)d_in[23];
  const float* gVH = (const float*)d_in[24]; const float* betaVH = (const float*)d_in[25];
  const float* W1 = (const float*)d_in[26]; const float* b1 = (const float*)d_in[27];
  const float* W2 = (const float*)d_in[28]; const float* b2 = (const float*)d_in[29];
  const float* g1 = (const float*)d_in[30]; const float* beta1 = (const float*)d_in[31];

  float* q_ws  = (float*)d_ws;
  float* k_ws  = q_ws + (size_t)ROWS * DM;
  float* v_ws  = k_ws + (size_t)ROWS * DM;
  float* ao_ws = v_ws + (size_t)ROWS * DM;

  QkvArgs A;
  A.state = state; A.H = H;
  A.br[0] = BranchArgs{Wq, bq, Wcq, bcq, gQE, betaQE, gQH, betaQH, q_ws};
  A.br[1] = BranchArgs{Wk, bk, Wck, bck, gKE, betaKE, gKH, betaKH, k_ws};
  A.br[2] = BranchArgs{Wv, bv, Wcv, bcv, gVE, betaVE, gVH, betaVH, v_ws};

  tb_qkv<<<ROWS / 64, 256, 0, stream>>>(A);
  tb_attn<<<dim3(5, 2, NBAT), 256, 0, stream>>>(q_ws, k_ws, v_ws, ao_ws);
  tb_ffn<<<ROWS / 64, 256, 0, stream>>>(state, ao_ws, W1, b1, W2, b2, g1, beta1, (float*)d_out);
}

// Round 2
// 304.162 us; speedup vs baseline: 1.7580x; 1.7580x over previous
//
#include <hip/hip_runtime.h>
#include <math.h>

namespace {

constexpr int SEQ  = 300;
constexpr int DM   = 64;
constexpr int DFFN = 256;
constexpr int NBAT = 256;
constexpr int ROWS = NBAT * SEQ;   // 76800
constexpr float EPS = 1e-5f;

typedef __attribute__((ext_vector_type(8))) short s16x8;
typedef __attribute__((ext_vector_type(4))) float f32x4;

__device__ __forceinline__ float4 ld4(const float* p) { return *reinterpret_cast<const float4*>(p); }

__device__ __forceinline__ ushort f2bf(float x) {
  unsigned u = __builtin_bit_cast(unsigned, x);
  u += 0x7FFFu + ((u >> 16) & 1u);
  return (ushort)(u >> 16);
}

struct BranchArgs {
  const float *W, *b, *Wc, *bc, *gE, *betaE, *gH, *betaH;
};
struct QkvArgs {
  const float *state, *H;
  BranchArgs br[3];
  ushort *qo, *ko, *vo;   // q,k: [b][h][300][32] bf16 ; v: [b][h][32][300] bf16 (transposed)
};

// ---------------------------------------------------------------------------
// K1: q/k/v = LN(state@W + b) * LN(H@Wc + bc) -> bf16 head-split layouts
// ---------------------------------------------------------------------------
__global__ __launch_bounds__(256) void tb_qkv(QkvArgs A)
{
  __shared__ float s_t[64][68];   // state^T [i][r]
  __shared__ float h_t[64][68];   // H^T chunk [i][r]
  const int t  = threadIdx.x;
  const int jg = t & 15, rg = t >> 4;
  const int j0 = jg * 4, r0 = rg * 4;
  const int rowbase = blockIdx.x * 64;

  #pragma unroll
  for (int it = 0; it < 4; ++it) {
    const int p = it * 256 + t;
    const int row = p >> 4, c4 = (p & 15) * 4;
    const float4 f = ld4(&A.state[(rowbase + row) * DM + c4]);
    s_t[c4 + 0][row] = f.x; s_t[c4 + 1][row] = f.y;
    s_t[c4 + 2][row] = f.z; s_t[c4 + 3][row] = f.w;
  }
  __syncthreads();

  float e[3][4][4];
  float h[3][4][4];
  #pragma unroll
  for (int br = 0; br < 3; ++br) {
    float bb[4]; *(float4*)bb = ld4(&A.br[br].b[j0]);
    float bb2[4]; *(float4*)bb2 = ld4(&A.br[br].bc[j0]);
    #pragma unroll
    for (int rr = 0; rr < 4; ++rr)
      #pragma unroll
      for (int jj = 0; jj < 4; ++jj) { e[br][rr][jj] = bb[jj]; h[br][rr][jj] = bb2[jj]; }
  }

  // E-part: state @ W (K = 64)
  #pragma unroll 1
  for (int i = 0; i < 64; i += 4) {
    float sv[4][4];
    #pragma unroll
    for (int u = 0; u < 4; ++u) *(float4*)sv[u] = *(const float4*)&s_t[i + u][r0];
    #pragma unroll
    for (int u = 0; u < 4; ++u) {
      #pragma unroll
      for (int br = 0; br < 3; ++br) {
        float wv[4]; *(float4*)wv = ld4(&A.br[br].W[(i + u) * DM + j0]);
        #pragma unroll
        for (int rr = 0; rr < 4; ++rr)
          #pragma unroll
          for (int jj = 0; jj < 4; ++jj)
            e[br][rr][jj] = fmaf(sv[u][rr], wv[jj], e[br][rr][jj]);
      }
    }
  }

  // H-part: H @ Wc (K = 256, 4 staged chunks)
  #pragma unroll 1
  for (int c = 0; c < 4; ++c) {
    __syncthreads();
    #pragma unroll
    for (int it = 0; it < 4; ++it) {
      const int p = it * 256 + t;
      const int row = p >> 4, c4 = (p & 15) * 4;
      const float4 f = ld4(&A.H[(rowbase + row) * DFFN + c * 64 + c4]);
      h_t[c4 + 0][row] = f.x; h_t[c4 + 1][row] = f.y;
      h_t[c4 + 2][row] = f.z; h_t[c4 + 3][row] = f.w;
    }
    __syncthreads();
    #pragma unroll 1
    for (int i = 0; i < 64; i += 4) {
      float sv[4][4];
      #pragma unroll
      for (int u = 0; u < 4; ++u) *(float4*)sv[u] = *(const float4*)&h_t[i + u][r0];
      #pragma unroll
      for (int u = 0; u < 4; ++u) {
        #pragma unroll
        for (int br = 0; br < 3; ++br) {
          float wv[4]; *(float4*)wv = ld4(&A.br[br].Wc[(c * 64 + i + u) * DM + j0]);
          #pragma unroll
          for (int rr = 0; rr < 4; ++rr)
            #pragma unroll
            for (int jj = 0; jj < 4; ++jj)
              h[br][rr][jj] = fmaf(sv[u][rr], wv[jj], h[br][rr][jj]);
        }
      }
    }
  }

  // LN(e) * LN(h) -> bf16 stores
  const int hh = j0 >> 5, dk = j0 & 31;
  #pragma unroll
  for (int br = 0; br < 3; ++br) {
    float gE[4], bE[4], gH[4], bH[4];
    *(float4*)gE = ld4(&A.br[br].gE[j0]);
    *(float4*)bE = ld4(&A.br[br].betaE[j0]);
    *(float4*)gH = ld4(&A.br[br].gH[j0]);
    *(float4*)bH = ld4(&A.br[br].betaH[j0]);
    float ovv[4][4];
    #pragma unroll
    for (int rr = 0; rr < 4; ++rr) {
      float s1 = 0.f, s2 = 0.f, t1 = 0.f, t2 = 0.f;
      #pragma unroll
      for (int jj = 0; jj < 4; ++jj) {
        s1 += e[br][rr][jj]; s2 += e[br][rr][jj] * e[br][rr][jj];
        t1 += h[br][rr][jj]; t2 += h[br][rr][jj] * h[br][rr][jj];
      }
      #pragma unroll
      for (int m = 1; m <= 8; m <<= 1) {
        s1 += __shfl_xor(s1, m, 64); s2 += __shfl_xor(s2, m, 64);
        t1 += __shfl_xor(t1, m, 64); t2 += __shfl_xor(t2, m, 64);
      }
      const float me = s1 * (1.f / 64.f);
      const float re = rsqrtf(s2 * (1.f / 64.f) - me * me + EPS);
      const float mh = t1 * (1.f / 64.f);
      const float rh = rsqrtf(t2 * (1.f / 64.f) - mh * mh + EPS);
      #pragma unroll
      for (int jj = 0; jj < 4; ++jj) {
        const float en = (e[br][rr][jj] - me) * re * gE[jj] + bE[jj];
        const float hn = (h[br][rr][jj] - mh) * rh * gH[jj] + bH[jj];
        ovv[rr][jj] = en * hn;
      }
    }
    if (br == 2) {
      // V^T store: [b][h][32 d][300 s]; 4-row group never straddles a batch
      const int row0 = rowbase + r0;
      const int bb = row0 / 300;
      const int ss0 = row0 - bb * 300;
      ushort* dst = A.vo + ((size_t)(bb * 2 + hh) * 32) * 300;
      #pragma unroll
      for (int jj = 0; jj < 4; ++jj) {
        ushort4 pk;
        pk.x = f2bf(ovv[0][jj]); pk.y = f2bf(ovv[1][jj]);
        pk.z = f2bf(ovv[2][jj]); pk.w = f2bf(ovv[3][jj]);
        *(ushort4*)&dst[(dk + jj) * 300 + ss0] = pk;
      }
    } else {
      ushort* dst = (br == 0) ? A.qo : A.ko;
      const float sc = (br == 0) ? 0.17677669529663687f : 1.f;  // fold 1/sqrt(32) into Q
      #pragma unroll
      for (int rr = 0; rr < 4; ++rr) {
        const int row = rowbase + r0 + rr;
        const int bb = row / 300;
        const int ss = row - bb * 300;
        ushort4 pk;
        pk.x = f2bf(ovv[rr][0] * sc); pk.y = f2bf(ovv[rr][1] * sc);
        pk.z = f2bf(ovv[rr][2] * sc); pk.w = f2bf(ovv[rr][3] * sc);
        *(ushort4*)&dst[((size_t)(bb * 2 + hh) * 300 + ss) * 32 + dk] = pk;
      }
    }
  }
}

// ---------------------------------------------------------------------------
// K2: bf16 MFMA attention. Block = (h, b). S^T = mfma(K,Q) -> in-register
// softmax (lane holds k-slice of one q-row) -> P bf16 regs -> PV MFMA.
// ---------------------------------------------------------------------------
__global__ __launch_bounds__(256, 2) void tb_attn(const ushort* __restrict__ q,
    const ushort* __restrict__ k, const ushort* __restrict__ vt, float* __restrict__ ao)
{
  __shared__ __align__(16) char lq[304 * 64];    // Q rows, 64B, XOR-swizzled
  __shared__ __align__(16) char lk[304 * 64];    // K rows, 64B, XOR-swizzled
  __shared__ __align__(16) char lv[32 * 656];    // V^T rows [d][328 bf16] (pad)

  const int t = threadIdx.x;
  const int hh = blockIdx.x, b = blockIdx.y;
  const size_t bh = (size_t)(b * 2 + hh);

  const char* qg = (const char*)(q + bh * 300 * 32);
  const char* kg = (const char*)(k + bh * 300 * 32);
  const char* vg = (const char*)(vt + bh * 32 * 300);

  // stage Q and K (zero-fill rows 300..303), swizzle: a ^= (a>>2)&0x70
  for (int c = t; c < 1216; c += 256) {
    const int lin = c * 16;
    const int row = c >> 2;
    uint4 val = make_uint4(0u, 0u, 0u, 0u);
    if (row < 300) val = *(const uint4*)(qg + lin);
    *(uint4*)(lq + (lin ^ ((lin >> 2) & 0x70))) = val;
  }
  for (int c = t; c < 1216; c += 256) {
    const int lin = c * 16;
    const int row = c >> 2;
    uint4 val = make_uint4(0u, 0u, 0u, 0u);
    if (row < 300) val = *(const uint4*)(kg + lin);
    *(uint4*)(lk + (lin ^ ((lin >> 2) & 0x70))) = val;
  }
  // V^T: zero pad cols [300,320), copy cols [0,300)
  for (int i = t; i < 320; i += 256) {
    const int row = i / 10, cc = i - row * 10;
    *(unsigned*)(lv + row * 656 + 600 + cc * 4) = 0u;
  }
  for (int i = t; i < 2400; i += 256) {
    const int row = i / 75, cc = i - row * 75;
    *(uint2*)(lv + row * 656 + cc * 8) = *(const uint2*)(vg + row * 600 + cc * 8);
  }
  __syncthreads();

  const int lane = t & 63, wid = t >> 6;
  const int lo = lane & 15, hi = lane >> 4;
  const f32x4 zero = {0.f, 0.f, 0.f, 0.f};

  for (int qt = wid; qt < 19; qt += 4) {
    // Q fragment: lane -> q row (qt*16+lo), 8 dk at hi*16 bytes
    int qa = (qt * 16 + lo) * 64 + hi * 16;
    qa ^= (qa >> 2) & 0x70;
    const s16x8 qf = *(const s16x8*)(lq + qa);

    // S^T tiles: p[kt][r] = S[k = kt*16+hi*4+r][q = qt*16+lo]
    f32x4 p[19];
    #pragma unroll
    for (int kt = 0; kt < 19; ++kt) {
      int ka = (kt * 16 + lo) * 64 + hi * 16;
      ka ^= (ka >> 2) & 0x70;
      const s16x8 kf = *(const s16x8*)(lk + ka);
      p[kt] = __builtin_amdgcn_mfma_f32_16x16x32_bf16(kf, qf, zero, 0, 0, 0);
    }

    // softmax over k (per q-row spread over lanes lo, lo+16, lo+32, lo+48)
    float mx = -1e30f;
    #pragma unroll
    for (int kt = 0; kt < 19; ++kt)
      #pragma unroll
      for (int r = 0; r < 4; ++r) mx = fmaxf(mx, p[kt][r]);
    mx = fmaxf(mx, __shfl_xor(mx, 16, 64));
    mx = fmaxf(mx, __shfl_xor(mx, 32, 64));

    #pragma unroll
    for (int kt = 0; kt < 19; ++kt)
      #pragma unroll
      for (int r = 0; r < 4; ++r) p[kt][r] = __expf(p[kt][r] - mx);
    if (hi == 3) p[18] = zero;   // k rows 300..303 are pad

    float sum = 0.f;
    #pragma unroll
    for (int kt = 0; kt < 19; ++kt)
      #pragma unroll
      for (int r = 0; r < 4; ++r) sum += p[kt][r];
    sum += __shfl_xor(sum, 16, 64);
    sum += __shfl_xor(sum, 32, 64);
    const float inv = 1.f / sum;

    // pack P -> bf16x8 fragments: pair pr covers k-tiles (2pr, 2pr+1)
    s16x8 pb[10];
    #pragma unroll
    for (int pr = 0; pr < 9; ++pr) {
      uint4 w;
      w.x = (unsigned)f2bf(p[2*pr][0] * inv)   | ((unsigned)f2bf(p[2*pr][1] * inv) << 16);
      w.y = (unsigned)f2bf(p[2*pr][2] * inv)   | ((unsigned)f2bf(p[2*pr][3] * inv) << 16);
      w.z = (unsigned)f2bf(p[2*pr+1][0] * inv) | ((unsigned)f2bf(p[2*pr+1][1] * inv) << 16);
      w.w = (unsigned)f2bf(p[2*pr+1][2] * inv) | ((unsigned)f2bf(p[2*pr+1][3] * inv) << 16);
      pb[pr] = __builtin_bit_cast(s16x8, w);
    }
    {
      uint4 w;
      w.x = (unsigned)f2bf(p[18][0] * inv) | ((unsigned)f2bf(p[18][1] * inv) << 16);
      w.y = (unsigned)f2bf(p[18][2] * inv) | ((unsigned)f2bf(p[18][3] * inv) << 16);
      w.z = 0u; w.w = 0u;                    // k-tile 19 = all pad
      pb[9] = __builtin_bit_cast(s16x8, w);
    }

    // PV: out[q][d] ; B-frag lane = d (lo / lo+16), elems = 8 k from V^T rows
    f32x4 acc0 = zero, acc1 = zero;
    #pragma unroll
    for (int pr = 0; pr < 10; ++pr) {
      const int byte0 = pr * 64 + hi * 8;
      uint4 w0, w1;
      {
        const uint2 a = *(const uint2*)(lv + lo * 656 + byte0);
        const uint2 c = *(const uint2*)(lv + lo * 656 + byte0 + 32);
        w0.x = a.x; w0.y = a.y; w0.z = c.x; w0.w = c.y;
      }
      {
        const uint2 a = *(const uint2*)(lv + (lo + 16) * 656 + byte0);
        const uint2 c = *(const uint2*)(lv + (lo + 16) * 656 + byte0 + 32);
        w1.x = a.x; w1.y = a.y; w1.z = c.x; w1.w = c.y;
      }
      acc0 = __builtin_amdgcn_mfma_f32_16x16x32_bf16(pb[pr], __builtin_bit_cast(s16x8, w0), acc0, 0, 0, 0);
      acc1 = __builtin_amdgcn_mfma_f32_16x16x32_bf16(pb[pr], __builtin_bit_cast(s16x8, w1), acc1, 0, 0, 0);
    }

    // store: D layout row = q = hi*4+r, col = d = lo (+16)
    float* aop = ao + ((size_t)b * 300) * 64 + hh * 32;
    const int s0 = qt * 16 + hi * 4;
    #pragma unroll
    for (int r = 0; r < 4; ++r) {
      const int s = s0 + r;
      if (s < 300) {
        aop[s * 64 + lo]      = acc0[r];
        aop[s * 64 + 16 + lo] = acc1[r];
      }
    }
  }
}

// ---------------------------------------------------------------------------
// K3: Z1 = state + attn; Z2 = LN(Z1); Z3 = gelu(Z2@W1+b1); out = Z1 + Z3@W2 + b2
// ---------------------------------------------------------------------------
__global__ __launch_bounds__(256) void tb_ffn(const float* __restrict__ state, const float* __restrict__ ao,
    const float* __restrict__ W1, const float* __restrict__ b1,
    const float* __restrict__ W2, const float* __restrict__ b2,
    const float* __restrict__ g1, const float* __restrict__ beta1,
    float* __restrict__ out)
{
  __shared__ float Z1[64][68];
  __shared__ float Z2t[64][68];   // Z2^T [i][r]
  __shared__ float Z3t[64][68];   // gelu chunk ^T [i][r]
  const int t = threadIdx.x;
  const int rowbase = blockIdx.x * 64;

  #pragma unroll
  for (int it = 0; it < 4; ++it) {
    const int p = it * 256 + t;
    const int row = p >> 4, c4 = (p & 15) * 4;
    const float4 a = ld4(&state[(rowbase + row) * DM + c4]);
    const float4 bo = ld4(&ao[(rowbase + row) * DM + c4]);
    float zv[4] = {a.x + bo.x, a.y + bo.y, a.z + bo.z, a.w + bo.w};
    *(float4*)&Z1[row][c4] = *(float4*)zv;
  }
  __syncthreads();

  {
    const int wv = t >> 6, lane = t & 63;
    const float g = g1[lane], be = beta1[lane];
    #pragma unroll 1
    for (int u = 0; u < 16; ++u) {
      const int r = wv * 16 + u;
      const float x = Z1[r][lane];
      float s1 = x, s2 = x * x;
      #pragma unroll
      for (int m = 1; m <= 32; m <<= 1) { s1 += __shfl_xor(s1, m, 64); s2 += __shfl_xor(s2, m, 64); }
      const float mean = s1 * (1.f / 64.f);
      const float rstd = rsqrtf(s2 * (1.f / 64.f) - mean * mean + EPS);
      Z2t[lane][r] = (x - mean) * rstd * g + be;
    }
  }
  __syncthreads();

  const int jg = t & 15, rg = t >> 4;
  const int j0 = jg * 4, r0 = rg * 4;
  float acc4[4][4];
  {
    float bb[4]; *(float4*)bb = ld4(&b2[j0]);
    #pragma unroll
    for (int rr = 0; rr < 4; ++rr)
      #pragma unroll
      for (int jj = 0; jj < 4; ++jj) acc4[rr][jj] = bb[jj];
  }

  #pragma unroll 1
  for (int c = 0; c < 4; ++c) {
    float acc1[4][4];
    {
      float bb[4]; *(float4*)bb = ld4(&b1[c * 64 + j0]);
      #pragma unroll
      for (int rr = 0; rr < 4; ++rr)
        #pragma unroll
        for (int jj = 0; jj < 4; ++jj) acc1[rr][jj] = bb[jj];
    }
    #pragma unroll 2
    for (int i = 0; i < 64; i += 4) {
      float zv[4][4];
      #pragma unroll
      for (int u = 0; u < 4; ++u) *(float4*)zv[u] = *(const float4*)&Z2t[i + u][r0];
      #pragma unroll
      for (int u = 0; u < 4; ++u) {
        float wv[4]; *(float4*)wv = ld4(&W1[(i + u) * DFFN + c * 64 + j0]);
        #pragma unroll
        for (int rr = 0; rr < 4; ++rr)
          #pragma unroll
          for (int jj = 0; jj < 4; ++jj)
            acc1[rr][jj] = fmaf(zv[u][rr], wv[jj], acc1[rr][jj]);
      }
    }
    #pragma unroll
    for (int rr = 0; rr < 4; ++rr)
      #pragma unroll
      for (int jj = 0; jj < 4; ++jj) {
        const float xg = acc1[rr][jj];
        Z3t[j0 + jj][r0 + rr] = 0.5f * xg * (1.f + erff(xg * 0.70710678118654752f));
      }
    __syncthreads();
    #pragma unroll 2
    for (int i = 0; i < 64; i += 4) {
      float zv[4][4];
      #pragma unroll
      for (int u = 0; u < 4; ++u) *(float4*)zv[u] = *(const float4*)&Z3t[i + u][r0];
      #pragma unroll
      for (int u = 0; u < 4; ++u) {
        float wv[4]; *(float4*)wv = ld4(&W2[(c * 64 + i + u) * DM + j0]);
        #pragma unroll
        for (int rr = 0; rr < 4; ++rr)
          #pragma unroll
          for (int jj = 0; jj < 4; ++jj)
            acc4[rr][jj] = fmaf(zv[u][rr], wv[jj], acc4[rr][jj]);
      }
    }
    __syncthreads();
  }

  #pragma unroll
  for (int rr = 0; rr < 4; ++rr) {
    float ov[4];
    const float* z1p = &Z1[r0 + rr][j0];
    #pragma unroll
    for (int jj = 0; jj < 4; ++jj) ov[jj] = z1p[jj] + acc4[rr][jj];
    *(float4*)&out[(rowbase + r0 + rr) * DM + j0] = *(float4*)ov;
  }
}

} // namespace

extern "C" void kernel_launch(void* const* d_in, const int* in_sizes, int n_in,
                              void* d_out, int out_size, void* d_ws, size_t ws_size,
                              hipStream_t stream)
{
  const float* state = (const float*)d_in[0];
  const float* H     = (const float*)d_in[1];
  const float* Wq  = (const float*)d_in[2];  const float* bq  = (const float*)d_in[3];
  const float* Wk  = (const float*)d_in[4];  const float* bk  = (const float*)d_in[5];
  const float* Wv  = (const float*)d_in[6];  const float* bv  = (const float*)d_in[7];
  const float* Wcq = (const float*)d_in[8];  const float* bcq = (const float*)d_in[9];
  const float* Wck = (const float*)d_in[10]; const float* bck = (const float*)d_in[11];
  const float* Wcv = (const float*)d_in[12]; const float* bcv = (const float*)d_in[13];
  const float* gQE = (const float*)d_in[14]; const float* betaQE = (const float*)d_in[15];
  const float* gKE = (const float*)d_in[16]; const float* betaKE = (const float*)d_in[17];
  const float* gVE = (const float*)d_in[18]; const float* betaVE = (const float*)d_in[19];
  const float* gQH = (const float*)d_in[20]; const float* betaQH = (const float*)d_in[21];
  const float* gKH = (const float*)d_in[22]; const float* betaKH = (const float*)d_in[23];
  const float* gVH = (const float*)d_in[24]; const float* betaVH = (const float*)d_in[25];
  const float* W1 = (const float*)d_in[26]; const float* b1 = (const float*)d_in[27];
  const float* W2 = (const float*)d_in[28]; const float* b2 = (const float*)d_in[29];
  const float* g1 = (const float*)d_in[30]; const float* beta1 = (const float*)d_in[31];

  constexpr size_t QKV_ELEMS = (size_t)NBAT * 2 * 300 * 32;   // 4,915,200 bf16
  ushort* q_ws = (ushort*)d_ws;
  ushort* k_ws = q_ws + QKV_ELEMS;
  ushort* v_ws = k_ws + QKV_ELEMS;
  float*  ao_ws = (float*)(v_ws + QKV_ELEMS);                  // fp32 [ROWS][64]

  QkvArgs A;
  A.state = state; A.H = H;
  A.br[0] = BranchArgs{Wq, bq, Wcq, bcq, gQE, betaQE, gQH, betaQH};
  A.br[1] = BranchArgs{Wk, bk, Wck, bck, gKE, betaKE, gKH, betaKH};
  A.br[2] = BranchArgs{Wv, bv, Wcv, bcv, gVE, betaVE, gVH, betaVH};
  A.qo = q_ws; A.ko = k_ws; A.vo = v_ws;

  tb_qkv<<<ROWS / 64, 256, 0, stream>>>(A);
  tb_attn<<<dim3(2, NBAT), 256, 0, stream>>>(q_ws, k_ws, v_ws, ao_ws);
  tb_ffn<<<ROWS / 64, 256, 0, stream>>>(state, ao_ws, W1, b1, W2, b2, g1, beta1, (float*)d_out);
}

// Round 3
// 146.605 us; speedup vs baseline: 3.6474x; 2.0747x over previous
//
#include <hip/hip_runtime.h>
#include <math.h>

namespace {

constexpr int SEQ  = 300;
constexpr int DM   = 64;
constexpr int DFFN = 256;
constexpr int NBAT = 256;
constexpr int ROWS = NBAT * SEQ;   // 76800
constexpr float EPS = 1e-5f;

typedef __attribute__((ext_vector_type(8))) short s16x8;
typedef __attribute__((ext_vector_type(4))) float f32x4;

__device__ __forceinline__ float4 ld4(const float* p) { return *reinterpret_cast<const float4*>(p); }

__device__ __forceinline__ ushort f2bf(float x) {
  unsigned u = __builtin_bit_cast(unsigned, x);
  u += 0x7FFFu + ((u >> 16) & 1u);
  return (ushort)(u >> 16);
}

// ---------------------------------------------------------------------------
// Prep: pack weights to bf16, transposed [n][k], rows of 128B, pre-swizzled
// (byte ^ ((n&7)<<4)) so GEMM staging is a linear copy and ds_read_b128 is
// 2-way max. Also packs biases + LN params for qkv.
// ---------------------------------------------------------------------------
struct PrepArgs {
  const float *Wq,*Wk,*Wv,*Wcq,*Wck,*Wcv;
  const float *bq,*bk,*bv,*bcq,*bck,*bcv;
  const float *gQE,*betaQE,*gKE,*betaKE,*gVE,*betaVE;
  const float *gQH,*betaQH,*gKH,*betaKH,*gVH,*betaVH;
  const float *W1,*W2;
  ushort *Bqkv, *W1t, *W2t;
  float *pk;   // bE[192] bH[192] gE[192] betaE[192] gH[192] betaH[192]
};

__global__ __launch_bounds__(256) void tb_prep(PrepArgs P) {
  const int idx = blockIdx.x * 256 + threadIdx.x;
  if (idx < 61440) {                       // Bqkv [5 chunks][192 n][64 k]
    const int c = idx / 12288, rem = idx % 12288;
    const int n = rem >> 6, k = rem & 63;
    const int br = n >> 6, col = n & 63;
    float v;
    if (c == 0) {
      const float* W = (br == 0) ? P.Wq : (br == 1) ? P.Wk : P.Wv;
      v = W[k * DM + col];
    } else {
      const float* W = (br == 0) ? P.Wcq : (br == 1) ? P.Wck : P.Wcv;
      v = W[((c - 1) * 64 + k) * DM + col];
    }
    P.Bqkv[c * 12288 + ((n * 128 + ((k * 2) ^ ((n & 7) << 4))) >> 1)] = f2bf(v);
  } else if (idx < 77824) {                // W1t [256 n][64 k]
    const int r = idx - 61440, n = r >> 6, k = r & 63;
    P.W1t[(n * 128 + ((k * 2) ^ ((n & 7) << 4))) >> 1] = f2bf(P.W1[k * DFFN + n]);
  } else if (idx < 94208) {                // W2t [4 kc][64 n][64 k]
    const int r = idx - 77824, kc = r >> 12, rem = r & 4095;
    const int n = rem >> 6, k = rem & 63;
    P.W2t[kc * 4096 + ((n * 128 + ((k * 2) ^ ((n & 7) << 4))) >> 1)] =
        f2bf(P.W2[(kc * 64 + k) * DM + n]);
  } else if (idx < 95360) {                // packed bias/LN params
    const int r = idx - 94208, which = r / 192, j = r % 192;
    const int br = j >> 6, col = j & 63;
    const float* s;
    switch (which) {
      case 0:  s = (br==0)?P.bq   :(br==1)?P.bk    :P.bv;     break;
      case 1:  s = (br==0)?P.bcq  :(br==1)?P.bck   :P.bcv;    break;
      case 2:  s = (br==0)?P.gQE  :(br==1)?P.gKE   :P.gVE;    break;
      case 3:  s = (br==0)?P.betaQE:(br==1)?P.betaKE:P.betaVE; break;
      case 4:  s = (br==0)?P.gQH  :(br==1)?P.gKH   :P.gVH;    break;
      default: s = (br==0)?P.betaQH:(br==1)?P.betaKH:P.betaVH; break;
    }
    P.pk[which * 192 + j] = s[col];
  }
}

// ---------------------------------------------------------------------------
// K1: q/k/v via MFMA. Block = 64 rows, 4 waves m-split (wave = 16 rows x 192
// cols so LN is wave-local). K-chunks of 64: chunk0 = state@W, 1-4 = H@Wc.
// ---------------------------------------------------------------------------
struct QkvArgs {
  const float *state, *H;
  const ushort *Bqkv;
  const float *pk;
  ushort *qo, *ko, *vo;  // q,k: [bh][300][32] ; v: [bh][32][300]
};

__global__ __launch_bounds__(256) void tb_qkv(QkvArgs A) {
  __shared__ __align__(16) ushort Ab[4608];    // A chunk [64][64] swizzled (+V xpose buf)
  __shared__ __align__(16) ushort Bb[12288];   // B chunk [192][64] swizzled
  const int t = threadIdx.x;
  const int lane = t & 63, w = t >> 6;
  const int lo = lane & 15, hi = lane >> 4;
  const int rowbase = blockIdx.x * 64;

  f32x4 accE[12], accH[12];
  #pragma unroll
  for (int nt = 0; nt < 12; ++nt) {
    const float bE = A.pk[nt * 16 + lo], bH = A.pk[192 + nt * 16 + lo];
    accE[nt] = (f32x4){bE, bE, bE, bE};
    accH[nt] = (f32x4){bH, bH, bH, bH};
  }

  const int arow = w * 16 + lo;
  const int aswz = (lo & 7) << 4;

#define STAGE_B(c)                                                            \
  _Pragma("unroll")                                                           \
  for (int i = 0; i < 6; ++i) {                                               \
    const int s_ = i * 256 + t;                                               \
    *(uint4*)&Bb[s_ * 8] = *(const uint4*)&A.Bqkv[(c) * 12288 + s_ * 8];      \
  }

#define STAGE_A(SRC, STRIDE)                                                  \
  _Pragma("unroll")                                                           \
  for (int i = 0; i < 4; ++i) {                                               \
    const int p_ = i * 256 + t;                                               \
    const int row_ = p_ >> 4, slot_ = p_ & 15;                                \
    const float4 f_ = ld4(&(SRC)[row_ * (STRIDE) + slot_ * 4]);               \
    ushort4 u_;                                                               \
    u_.x = f2bf(f_.x); u_.y = f2bf(f_.y); u_.z = f2bf(f_.z); u_.w = f2bf(f_.w);\
    *(ushort4*)((char*)Ab + (row_ * 128 + ((slot_ * 8) ^ ((row_ & 7) << 4)))) = u_; \
  }

#define COMPUTE(ACC)                                                          \
  _Pragma("unroll")                                                           \
  for (int ks = 0; ks < 2; ++ks) {                                            \
    const s16x8 af = *(const s16x8*)((const char*)Ab +                        \
        (arow * 128 + ((ks * 64 + hi * 16) ^ aswz)));                         \
    _Pragma("unroll")                                                         \
    for (int nt = 0; nt < 12; ++nt) {                                         \
      const int n_ = nt * 16 + lo;                                            \
      const s16x8 bf = *(const s16x8*)((const char*)Bb +                      \
          (n_ * 128 + ((ks * 64 + hi * 16) ^ ((n_ & 7) << 4))));              \
      ACC[nt] = __builtin_amdgcn_mfma_f32_16x16x32_bf16(af, bf, ACC[nt], 0, 0, 0); \
    }                                                                         \
  }

  STAGE_B(0)
  STAGE_A(A.state + (size_t)rowbase * 64, 64)
  __syncthreads();
  COMPUTE(accE)
  for (int c = 1; c < 5; ++c) {
    __syncthreads();
    STAGE_B(c)
    const float* hsrc = A.H + (size_t)rowbase * 256 + (c - 1) * 64;
    STAGE_A(hsrc, 256)
    __syncthreads();
    COMPUTE(accH)
  }
#undef STAGE_B
#undef STAGE_A
#undef COMPUTE

  // epilogue: dual LN + gate, store q/k direct, v via LDS transpose
  const float* gE  = A.pk + 384;
  const float* bEt = A.pk + 576;
  const float* gH  = A.pk + 768;
  const float* bHt = A.pk + 960;
  const int growbase = rowbase + w * 16 + hi * 4;
  float vout[4][4];

  #pragma unroll
  for (int br = 0; br < 3; ++br) {
    #pragma unroll
    for (int r = 0; r < 4; ++r) {
      float s1 = 0.f, s2 = 0.f, u1 = 0.f, u2 = 0.f;
      #pragma unroll
      for (int qq = 0; qq < 4; ++qq) {
        const float ev = accE[br * 4 + qq][r], hv = accH[br * 4 + qq][r];
        s1 += ev; s2 += ev * ev; u1 += hv; u2 += hv * hv;
      }
      #pragma unroll
      for (int m = 1; m <= 8; m <<= 1) {
        s1 += __shfl_xor(s1, m, 64); s2 += __shfl_xor(s2, m, 64);
        u1 += __shfl_xor(u1, m, 64); u2 += __shfl_xor(u2, m, 64);
      }
      const float me = s1 * (1.f / 64.f);
      const float re = rsqrtf(s2 * (1.f / 64.f) - me * me + EPS);
      const float mh = u1 * (1.f / 64.f);
      const float rh = rsqrtf(u2 * (1.f / 64.f) - mh * mh + EPS);
      const int grow = growbase + r;
      const int bb = grow / 300, ss = grow - bb * 300;
      #pragma unroll
      for (int qq = 0; qq < 4; ++qq) {
        const int colg = (br * 4 + qq) * 16 + lo;
        const float en = (accE[br * 4 + qq][r] - me) * re * gE[colg] + bEt[colg];
        const float hn = (accH[br * 4 + qq][r] - mh) * rh * gH[colg] + bHt[colg];
        const float val = en * hn;
        if (br == 2) {
          vout[r][qq] = val;
        } else {
          const int cb = qq * 16 + lo;      // col within branch
          const int hh = cb >> 5, dk = cb & 31;
          ushort* dst = (br == 0) ? A.qo : A.ko;
          const float sc = (br == 0) ? 0.17677669529663687f : 1.f;
          dst[((size_t)(bb * 2 + hh) * 300 + ss) * 32 + dk] = f2bf(val * sc);
        }
      }
    }
  }

  __syncthreads();
  ushort* vbuf = Ab;  // [64 dk][68 s]
  #pragma unroll
  for (int r = 0; r < 4; ++r) {
    const int sl = w * 16 + hi * 4 + r;
    #pragma unroll
    for (int qq = 0; qq < 4; ++qq) {
      const int dk = qq * 16 + lo;
      vbuf[dk * 68 + sl] = f2bf(vout[r][qq]);
    }
  }
  __syncthreads();
  #pragma unroll
  for (int i = 0; i < 4; ++i) {
    const int p = i * 256 + t;
    const int dk = p >> 4, sg = p & 15;
    const int grow = rowbase + sg * 4;
    const int bb = grow / 300, ss = grow - bb * 300;
    const int hh = dk >> 5, dkh = dk & 31;
    ushort4 val;
    val.x = vbuf[dk * 68 + sg * 4 + 0];
    val.y = vbuf[dk * 68 + sg * 4 + 1];
    val.z = vbuf[dk * 68 + sg * 4 + 2];
    val.w = vbuf[dk * 68 + sg * 4 + 3];
    *(ushort4*)&A.vo[(size_t)(bb * 2 + hh) * 9600 + dkh * 300 + ss] = val;
  }
}

// ---------------------------------------------------------------------------
// K2: bf16 MFMA attention (unchanged from R2 - verified).
// ---------------------------------------------------------------------------
__global__ __launch_bounds__(256, 2) void tb_attn(const ushort* __restrict__ q,
    const ushort* __restrict__ k, const ushort* __restrict__ vt, float* __restrict__ ao)
{
  __shared__ __align__(16) char lq[304 * 64];
  __shared__ __align__(16) char lk[304 * 64];
  __shared__ __align__(16) char lv[32 * 656];

  const int t = threadIdx.x;
  const int hh = blockIdx.x, b = blockIdx.y;
  const size_t bh = (size_t)(b * 2 + hh);

  const char* qg = (const char*)(q + bh * 300 * 32);
  const char* kg = (const char*)(k + bh * 300 * 32);
  const char* vg = (const char*)(vt + bh * 32 * 300);

  for (int c = t; c < 1216; c += 256) {
    const int lin = c * 16;
    const int row = c >> 2;
    uint4 val = make_uint4(0u, 0u, 0u, 0u);
    if (row < 300) val = *(const uint4*)(qg + lin);
    *(uint4*)(lq + (lin ^ ((lin >> 2) & 0x70))) = val;
  }
  for (int c = t; c < 1216; c += 256) {
    const int lin = c * 16;
    const int row = c >> 2;
    uint4 val = make_uint4(0u, 0u, 0u, 0u);
    if (row < 300) val = *(const uint4*)(kg + lin);
    *(uint4*)(lk + (lin ^ ((lin >> 2) & 0x70))) = val;
  }
  for (int i = t; i < 320; i += 256) {
    const int row = i / 10, cc = i - row * 10;
    *(unsigned*)(lv + row * 656 + 600 + cc * 4) = 0u;
  }
  for (int i = t; i < 2400; i += 256) {
    const int row = i / 75, cc = i - row * 75;
    *(uint2*)(lv + row * 656 + cc * 8) = *(const uint2*)(vg + row * 600 + cc * 8);
  }
  __syncthreads();

  const int lane = t & 63, wid = t >> 6;
  const int lo = lane & 15, hi = lane >> 4;
  const f32x4 zero = {0.f, 0.f, 0.f, 0.f};

  for (int qt = wid; qt < 19; qt += 4) {
    int qa = (qt * 16 + lo) * 64 + hi * 16;
    qa ^= (qa >> 2) & 0x70;
    const s16x8 qf = *(const s16x8*)(lq + qa);

    f32x4 p[19];
    #pragma unroll
    for (int kt = 0; kt < 19; ++kt) {
      int ka = (kt * 16 + lo) * 64 + hi * 16;
      ka ^= (ka >> 2) & 0x70;
      const s16x8 kf = *(const s16x8*)(lk + ka);
      p[kt] = __builtin_amdgcn_mfma_f32_16x16x32_bf16(kf, qf, zero, 0, 0, 0);
    }

    float mx = -1e30f;
    #pragma unroll
    for (int kt = 0; kt < 19; ++kt)
      #pragma unroll
      for (int r = 0; r < 4; ++r) mx = fmaxf(mx, p[kt][r]);
    mx = fmaxf(mx, __shfl_xor(mx, 16, 64));
    mx = fmaxf(mx, __shfl_xor(mx, 32, 64));

    #pragma unroll
    for (int kt = 0; kt < 19; ++kt)
      #pragma unroll
      for (int r = 0; r < 4; ++r) p[kt][r] = __expf(p[kt][r] - mx);
    if (hi == 3) p[18] = zero;

    float sum = 0.f;
    #pragma unroll
    for (int kt = 0; kt < 19; ++kt)
      #pragma unroll
      for (int r = 0; r < 4; ++r) sum += p[kt][r];
    sum += __shfl_xor(sum, 16, 64);
    sum += __shfl_xor(sum, 32, 64);
    const float inv = 1.f / sum;

    s16x8 pb[10];
    #pragma unroll
    for (int pr = 0; pr < 9; ++pr) {
      uint4 wv;
      wv.x = (unsigned)f2bf(p[2*pr][0] * inv)   | ((unsigned)f2bf(p[2*pr][1] * inv) << 16);
      wv.y = (unsigned)f2bf(p[2*pr][2] * inv)   | ((unsigned)f2bf(p[2*pr][3] * inv) << 16);
      wv.z = (unsigned)f2bf(p[2*pr+1][0] * inv) | ((unsigned)f2bf(p[2*pr+1][1] * inv) << 16);
      wv.w = (unsigned)f2bf(p[2*pr+1][2] * inv) | ((unsigned)f2bf(p[2*pr+1][3] * inv) << 16);
      pb[pr] = __builtin_bit_cast(s16x8, wv);
    }
    {
      uint4 wv;
      wv.x = (unsigned)f2bf(p[18][0] * inv) | ((unsigned)f2bf(p[18][1] * inv) << 16);
      wv.y = (unsigned)f2bf(p[18][2] * inv) | ((unsigned)f2bf(p[18][3] * inv) << 16);
      wv.z = 0u; wv.w = 0u;
      pb[9] = __builtin_bit_cast(s16x8, wv);
    }

    f32x4 acc0 = zero, acc1 = zero;
    #pragma unroll
    for (int pr = 0; pr < 10; ++pr) {
      const int byte0 = pr * 64 + hi * 8;
      uint4 w0, w1;
      {
        const uint2 a = *(const uint2*)(lv + lo * 656 + byte0);
        const uint2 c = *(const uint2*)(lv + lo * 656 + byte0 + 32);
        w0.x = a.x; w0.y = a.y; w0.z = c.x; w0.w = c.y;
      }
      {
        const uint2 a = *(const uint2*)(lv + (lo + 16) * 656 + byte0);
        const uint2 c = *(const uint2*)(lv + (lo + 16) * 656 + byte0 + 32);
        w1.x = a.x; w1.y = a.y; w1.z = c.x; w1.w = c.y;
      }
      acc0 = __builtin_amdgcn_mfma_f32_16x16x32_bf16(pb[pr], __builtin_bit_cast(s16x8, w0), acc0, 0, 0, 0);
      acc1 = __builtin_amdgcn_mfma_f32_16x16x32_bf16(pb[pr], __builtin_bit_cast(s16x8, w1), acc1, 0, 0, 0);
    }

    float* aop = ao + ((size_t)b * 300) * 64 + hh * 32;
    const int s0 = qt * 16 + hi * 4;
    #pragma unroll
    for (int r = 0; r < 4; ++r) {
      const int s = s0 + r;
      if (s < 300) {
        aop[s * 64 + lo]      = acc0[r];
        aop[s * 64 + 16 + lo] = acc1[r];
      }
    }
  }
}

// ---------------------------------------------------------------------------
// K3: FFN via MFMA. Block = 64 rows, 4 waves m-split.
// ---------------------------------------------------------------------------
struct FfnArgs {
  const float *state, *ao;
  const ushort *W1t, *W2t;
  const float *b1, *b2, *g1, *beta1;
  float* out;
};

__global__ __launch_bounds__(256) void tb_ffn(FfnArgs F) {
  __shared__ __align__(16) ushort Z2b[4096];    // [64][64] swizzled
  __shared__ __align__(16) ushort Wb[16384];    // W1t, then W2t
  __shared__ __align__(16) ushort Z3b[16384];   // [64][256] swizzled, rows 512B
  const int t = threadIdx.x;
  const int lane = t & 63, w = t >> 6;
  const int lo = lane & 15, hi = lane >> 4;
  const int rowbase = blockIdx.x * 64;

  #pragma unroll
  for (int i = 0; i < 8; ++i) {
    const int s_ = i * 256 + t;
    *(uint4*)&Wb[s_ * 8] = *(const uint4*)&F.W1t[s_ * 8];
  }
  {
    const float g = F.g1[lane], be = F.beta1[lane];
    #pragma unroll 1
    for (int u = 0; u < 16; ++u) {
      const int row = w * 16 + u;
      const size_t gidx = (size_t)(rowbase + row) * 64 + lane;
      const float x = F.state[gidx] + F.ao[gidx];
      float s1 = x, s2 = x * x;
      #pragma unroll
      for (int m = 1; m <= 32; m <<= 1) { s1 += __shfl_xor(s1, m, 64); s2 += __shfl_xor(s2, m, 64); }
      const float mean = s1 * (1.f / 64.f);
      const float rstd = rsqrtf(s2 * (1.f / 64.f) - mean * mean + EPS);
      const float z = (x - mean) * rstd * g + be;
      *(ushort*)((char*)Z2b + (row * 128 + ((lane * 2) ^ ((row & 7) << 4)))) = f2bf(z);
    }
  }
  __syncthreads();

  f32x4 acc1[16];
  #pragma unroll
  for (int nt = 0; nt < 16; ++nt) { const float b = F.b1[nt * 16 + lo]; acc1[nt] = (f32x4){b, b, b, b}; }
  {
    const int arow = w * 16 + lo;
    const int aswz = (lo & 7) << 4;
    #pragma unroll
    for (int ks = 0; ks < 2; ++ks) {
      const s16x8 af = *(const s16x8*)((const char*)Z2b + (arow * 128 + ((ks * 64 + hi * 16) ^ aswz)));
      #pragma unroll
      for (int nt = 0; nt < 16; ++nt) {
        const int n = nt * 16 + lo;
        const s16x8 bf = *(const s16x8*)((const char*)Wb + (n * 128 + ((ks * 64 + hi * 16) ^ ((n & 7) << 4))));
        acc1[nt] = __builtin_amdgcn_mfma_f32_16x16x32_bf16(af, bf, acc1[nt], 0, 0, 0);
      }
    }
  }
  __syncthreads();

  #pragma unroll
  for (int i = 0; i < 8; ++i) {
    const int s_ = i * 256 + t;
    *(uint4*)&Wb[s_ * 8] = *(const uint4*)&F.W2t[s_ * 8];
  }
  #pragma unroll
  for (int nt = 0; nt < 16; ++nt) {
    #pragma unroll
    for (int r = 0; r < 4; ++r) {
      const float xg = acc1[nt][r];
      const float gl = 0.5f * xg * (1.f + erff(xg * 0.70710678118654752f));
      const int row = w * 16 + hi * 4 + r;
      const int col = nt * 16 + lo;
      *(ushort*)((char*)Z3b + (row * 512 + ((col * 2) ^ ((row & 7) << 4)))) = f2bf(gl);
    }
  }
  __syncthreads();

  f32x4 acc2[4];
  #pragma unroll
  for (int nt = 0; nt < 4; ++nt) { const float b = F.b2[nt * 16 + lo]; acc2[nt] = (f32x4){b, b, b, b}; }
  {
    const int arow = w * 16 + lo;
    const int aswz = (lo & 7) << 4;
    #pragma unroll
    for (int ks = 0; ks < 8; ++ks) {
      const s16x8 af = *(const s16x8*)((const char*)Z3b + (arow * 512 + ((ks * 64 + hi * 16) ^ aswz)));
      const int kc = ks >> 1, k2 = ks & 1;
      #pragma unroll
      for (int nt = 0; nt < 4; ++nt) {
        const int n = nt * 16 + lo;
        const s16x8 bf = *(const s16x8*)((const char*)Wb +
            (kc * 8192 + n * 128 + ((k2 * 64 + hi * 16) ^ ((n & 7) << 4))));
        acc2[nt] = __builtin_amdgcn_mfma_f32_16x16x32_bf16(af, bf, acc2[nt], 0, 0, 0);
      }
    }
  }

  #pragma unroll
  for (int nt = 0; nt < 4; ++nt) {
    #pragma unroll
    for (int r = 0; r < 4; ++r) {
      const int grow = rowbase + w * 16 + hi * 4 + r;
      const int col = nt * 16 + lo;
      const size_t gidx = (size_t)grow * 64 + col;
      const float z1 = F.state[gidx] + F.ao[gidx];
      F.out[gidx] = z1 + acc2[nt][r];
    }
  }
}

} // namespace

extern "C" void kernel_launch(void* const* d_in, const int* in_sizes, int n_in,
                              void* d_out, int out_size, void* d_ws, size_t ws_size,
                              hipStream_t stream)
{
  const float* state = (const float*)d_in[0];
  const float* H     = (const float*)d_in[1];
  const float* Wq  = (const float*)d_in[2];  const float* bq  = (const float*)d_in[3];
  const float* Wk  = (const float*)d_in[4];  const float* bk  = (const float*)d_in[5];
  const float* Wv  = (const float*)d_in[6];  const float* bv  = (const float*)d_in[7];
  const float* Wcq = (const float*)d_in[8];  const float* bcq = (const float*)d_in[9];
  const float* Wck = (const float*)d_in[10]; const float* bck = (const float*)d_in[11];
  const float* Wcv = (const float*)d_in[12]; const float* bcv = (const float*)d_in[13];
  const float* gQE = (const float*)d_in[14]; const float* betaQE = (const float*)d_in[15];
  const float* gKE = (const float*)d_in[16]; const float* betaKE = (const float*)d_in[17];
  const float* gVE = (const float*)d_in[18]; const float* betaVE = (const float*)d_in[19];
  const float* gQH = (const float*)d_in[20]; const float* betaQH = (const float*)d_in[21];
  const float* gKH = (const float*)d_in[22]; const float* betaKH = (const float*)d_in[23];
  const float* gVH = (const float*)d_in[24]; const float* betaVH = (const float*)d_in[25];
  const float* W1 = (const float*)d_in[26]; const float* b1 = (const float*)d_in[27];
  const float* W2 = (const float*)d_in[28]; const float* b2 = (const float*)d_in[29];
  const float* g1 = (const float*)d_in[30]; const float* beta1 = (const float*)d_in[31];

  constexpr size_t QKV_E = (size_t)NBAT * 2 * 300 * 32;   // 4,915,200 bf16 per tensor
  float*  ao_ws = (float*)d_ws;                           // [ROWS][64] fp32
  ushort* q_ws  = (ushort*)(ao_ws + (size_t)ROWS * DM);
  ushort* k_ws  = q_ws + QKV_E;
  ushort* v_ws  = k_ws + QKV_E;
  ushort* Bqkv  = v_ws + QKV_E;        // 61440
  ushort* W1t   = Bqkv + 61440;        // 16384
  ushort* W2t   = W1t + 16384;         // 16384
  float*  pk    = (float*)(W2t + 16384);  // 1152 floats

  PrepArgs P;
  P.Wq = Wq; P.Wk = Wk; P.Wv = Wv; P.Wcq = Wcq; P.Wck = Wck; P.Wcv = Wcv;
  P.bq = bq; P.bk = bk; P.bv = bv; P.bcq = bcq; P.bck = bck; P.bcv = bcv;
  P.gQE = gQE; P.betaQE = betaQE; P.gKE = gKE; P.betaKE = betaKE;
  P.gVE = gVE; P.betaVE = betaVE; P.gQH = gQH; P.betaQH = betaQH;
  P.gKH = gKH; P.betaKH = betaKH; P.gVH = gVH; P.betaVH = betaVH;
  P.W1 = W1; P.W2 = W2;
  P.Bqkv = Bqkv; P.W1t = W1t; P.W2t = W2t; P.pk = pk;
  tb_prep<<<373, 256, 0, stream>>>(P);

  QkvArgs A;
  A.state = state; A.H = H; A.Bqkv = Bqkv; A.pk = pk;
  A.qo = q_ws; A.ko = k_ws; A.vo = v_ws;
  tb_qkv<<<ROWS / 64, 256, 0, stream>>>(A);

  tb_attn<<<dim3(2, NBAT), 256, 0, stream>>>(q_ws, k_ws, v_ws, ao_ws);

  FfnArgs F;
  F.state = state; F.ao = ao_ws; F.W1t = W1t; F.W2t = W2t;
  F.b1 = b1; F.b2 = b2; F.g1 = g1; F.beta1 = beta1; F.out = (float*)d_out;
  tb_ffn<<<ROWS / 64, 256, 0, stream>>>(F);
}